// Round 7
// baseline (140.732 us; speedup 1.0000x reference)
//
#include <hip/hip_runtime.h>

#define TT 8192
#define DD 64
#define MODS 4
#define NCH 256
#define CH  32    // TT / NCH

typedef __attribute__((ext_vector_type(8))) short bf16x8;
typedef __attribute__((ext_vector_type(4))) float f32x4;

// round-to-nearest-even fp32 -> bf16 bits
__device__ __forceinline__ unsigned f2bf1(float x) {
    unsigned u = __float_as_uint(x);
    return (u + 0x7FFFu + ((u >> 16) & 1u)) >> 16;
}
__device__ __forceinline__ unsigned packbf(float a, float b) {
    return f2bf1(a) | (f2bf1(b) << 16);
}

// stage one fp32 W layer [d][c] -> LDS bf16 W^T [c][d] (pitch 72 shorts).
__device__ __forceinline__ void stage_w(const float* __restrict__ Wl,
                                        unsigned short* wb, int c, int dp0)
{
    #pragma unroll
    for (int it = 0; it < 8; ++it) {
        int dp = dp0 + 4 * it;                    // 0..31 (pair of d's)
        float w0 = Wl[(2 * dp)     * DD + c];
        float w1 = Wl[(2 * dp + 1) * DD + c];
        *(unsigned*)&wb[c * 72 + 2 * dp] = packbf(w0, w1);
    }
}

// ---------------------------------------------------------------------------
// Kernel 1: fused MLP (bf16 MFMA) + chunk scan + time extraction.
// grid = (128 tiles of 64 rows, 5 jobs), block 256 = 4 waves.
//  - MLP identical to round 6 (W staged once/block double-buffered; x per-wave
//    in LDS; C layout m89-verified).
//  - During X staging (jobs>0): stash fp32 V[:, :2] and write fp32 times.
//  - After final layer (jobs>0): mirror K into kbuf (LDS), barrier, then the
//    block computes Ctot/Csub for its 2 chunks with the SAME serial FMA order
//    as the old scan_partial (bit-exact) — no 16 MB global K re-read.
// ---------------------------------------------------------------------------
__global__ __launch_bounds__(256)
void mlp_scan(const float* __restrict__ X,
              const float* __restrict__ wq_w, const float* __restrict__ wq_b,
              const float* __restrict__ wk_w, const float* __restrict__ wk_b,
              float* __restrict__ Q, float* __restrict__ Kout,
              float* __restrict__ Ctot, float* __restrict__ Csub,
              float* __restrict__ times)
{
    __shared__ unsigned short xbuf[4][16][72];   //  9,216 B
    __shared__ unsigned short wbuf[2][64][72];   // 18,432 B
    __shared__ float kbuf[64][68];               // 17,408 B
    __shared__ float2 vstash[64];                //    512 B

    const int job = blockIdx.y;
    const float *xin, *Wj, *Bias;
    float* out;
    if (job == 0) { xin = X; Wj = wq_w; Bias = wq_b; out = Q; }
    else {
        const int m = job - 1;
        xin  = X    + (size_t)m * TT * DD;
        Wj   = wk_w + (size_t)m * 3 * DD * DD;
        Bias = wk_b + (size_t)m * 3 * DD;
        out  = Kout + (size_t)m * TT * DD;
    }

    const int t    = threadIdx.x;
    const int wv   = t >> 6;
    const int lane = t & 63;
    const int quad = lane >> 4;
    const int l15  = lane & 15;
    const int row0 = blockIdx.x * 64 + wv * 16;   // this wave's 16 global rows
    unsigned short* xb = &xbuf[wv][0][0];
    const int wc = t & 63, wdp0 = t >> 6;

    // ---- stage this wave's 16x64 fp32 rows as bf16; stash fp32 V/time ----
    {
        const float4* src = (const float4*)(xin + (size_t)row0 * DD);
        #pragma unroll
        for (int k = 0; k < 4; ++k) {
            int f = lane + 64 * k;                // float4 idx 0..255
            int r = f >> 4, c4 = (f & 15) << 2;   // local-wave row, col
            float4 v = src[f];
            if (job > 0) {
                if ((f & 15) == 0)  vstash[wv * 16 + r] = make_float2(v.x, v.y);
                if ((f & 15) == 15) times[(size_t)(job - 1) * TT + row0 + r] = v.w;
            }
            uint2 p = make_uint2(packbf(v.x, v.y), packbf(v.z, v.w));
            *(uint2*)&xb[r * 72 + c4] = p;
        }
    }

    stage_w(Wj, &wbuf[0][0][0], wc, wdp0);

    #pragma unroll
    for (int l = 0; l < 3; ++l) {
        __syncthreads();
        const unsigned short* wb = &wbuf[l & 1][0][0];
        if (l < 2)
            stage_w(Wj + (size_t)(l + 1) * DD * DD, &wbuf[(l + 1) & 1][0][0], wc, wdp0);

        const float* Bl = Bias + l * DD;
        f32x4 acc[4];
        #pragma unroll
        for (int mt = 0; mt < 4; ++mt) {
            float4 b4 = *(const float4*)(Bl + 16 * mt + quad * 4);
            acc[mt][0] = b4.x; acc[mt][1] = b4.y; acc[mt][2] = b4.z; acc[mt][3] = b4.w;
        }

        bf16x8 xf[2];
        #pragma unroll
        for (int kt = 0; kt < 2; ++kt)
            xf[kt] = *(const bf16x8*)&xb[l15 * 72 + quad * 8 + kt * 32];

        #pragma unroll
        for (int mt = 0; mt < 4; ++mt) {
            #pragma unroll
            for (int kt = 0; kt < 2; ++kt) {
                bf16x8 wf = *(const bf16x8*)&wb[(16 * mt + l15) * 72 + quad * 8 + kt * 32];
                acc[mt] = __builtin_amdgcn_mfma_f32_16x16x32_bf16(wf, xf[kt], acc[mt], 0, 0, 0);
            }
        }

        if (l < 2) {
            #pragma unroll
            for (int mt = 0; mt < 4; ++mt) {
                float r0 = fmaxf(acc[mt][0], 0.f), r1 = fmaxf(acc[mt][1], 0.f);
                float r2 = fmaxf(acc[mt][2], 0.f), r3 = fmaxf(acc[mt][3], 0.f);
                uint2 p = make_uint2(packbf(r0, r1), packbf(r2, r3));
                *(uint2*)&xb[l15 * 72 + 16 * mt + quad * 4] = p;
            }
        } else {
            #pragma unroll
            for (int mt = 0; mt < 4; ++mt) {
                float4 v = make_float4(acc[mt][0], acc[mt][1], acc[mt][2], acc[mt][3]);
                *(float4*)(out + (size_t)(row0 + l15) * DD + 16 * mt + quad * 4) = v;
                if (job > 0)
                    *(float4*)(&kbuf[wv * 16 + l15][16 * mt + quad * 4]) = v;
            }
        }
    }

    // ---- fused chunk scan (jobs 1..4): 2 chunks of 32 rows per block ----
    if (job > 0) {
        __syncthreads();                          // kbuf/vstash complete
        const int m    = job - 1;
        const int chl  = t >> 7;                  // 0..1: local chunk
        const int tid2 = t & 127;
        const int d = tid2 & 63, e = tid2 >> 6;
        const int ch = blockIdx.x * 2 + chl;      // global chunk 0..255
        float acc = 0.f;
        #pragma unroll
        for (int j = 0; j < 4; ++j) {
            #pragma unroll
            for (int s = 0; s < 8; ++s) {
                const int rr = chl * 32 + j * 8 + s;
                float kv = kbuf[rr][d];
                float vv = e ? vstash[rr].y : vstash[rr].x;
                acc = fmaf(kv, vv, acc);
            }
            if (j < 3)
                Csub[(((size_t)m * NCH + ch) * 3 + j) * 128 + tid2] = acc;
        }
        Ctot[((size_t)m * NCH + ch) * 128 + tid2] = acc;
    }
}

// ---------------------------------------------------------------------------
// Kernel 2: fused prefix + search (independent given K1's outputs).
// blocks 0..3   : per-chunk EXCLUSIVE prefix PreC[m][c] over 256 chunks
//                 (two 128-chunk halves per block, LDS splice + RMW fixup).
// blocks 4..131 : per-(q,m) binary search over dense fp32 times (L1-hot).
// ---------------------------------------------------------------------------
__global__ __launch_bounds__(256)
void prefix_find(const float* __restrict__ Ctot, float* __restrict__ PreC,
                 const float* __restrict__ times, int* __restrict__ idx)
{
    const int b = blockIdx.x;
    if (b < MODS) {
        __shared__ float hs[128];
        const int sub = threadIdx.x >> 7, t = threadIdx.x & 127;
        const int c0 = sub * 128;
        float acc = 0.f;
        for (int c = c0; c < c0 + 128; ++c) {
            PreC[((size_t)b * NCH + c) * 128 + t] = acc;
            acc += Ctot[((size_t)b * NCH + c) * 128 + t];
        }
        if (sub == 0) hs[t] = acc;
        __syncthreads();
        if (sub == 1) {
            const float base = hs[t];
            for (int c = c0; c < c0 + 128; ++c)
                PreC[((size_t)b * NCH + c) * 128 + t] += base;
        }
    } else {
        const int bb = b - MODS;                  // 0..127
        const int m  = bb >> 5;
        const int q  = ((bb & 31) << 8) + threadIdx.x;
        const float t1 = times[q];                // modality-0 row IS t1
        const float* t2 = times + (size_t)m * TT;
        int lo = 0, hi = TT;
        #pragma unroll 1
        for (int s = 0; s < 13; ++s) {            // 2^13 == TT
            int mid = (lo + hi) >> 1;
            bool le = (t2[mid] <= t1);
            lo = le ? mid + 1 : lo;
            hi = le ? hi : mid;
        }
        idx[(size_t)m * TT + q] = lo - 1;         // searchsorted(right) - 1
    }
}

// ---------------------------------------------------------------------------
// Kernel 3: gather. One wave per (query, modality); no search, no Ctot loop:
// base = PreC[chunk] + Csub sub-chunk + <=8-row recompute. LDS combine.
// XCD swizzle keeps q-contiguous ranges per XCD (hot K/PreC slices in L2).
// ---------------------------------------------------------------------------
__global__ __launch_bounds__(256)
void gather_kernel(const float* __restrict__ X, const float* __restrict__ Q,
                   const float* __restrict__ Kin, const float* __restrict__ Csub,
                   const float* __restrict__ PreC, const int* __restrict__ idx,
                   float* __restrict__ out)
{
    const int bx   = blockIdx.x;
    const int q    = ((bx & 7) << 10) | (bx >> 3);   // XCD-contiguous q ranges
    const int m    = threadIdx.x >> 6;
    const int lane = threadIdx.x & 63;

    const float qv = Q[(size_t)q * DD + lane];
    const int id = idx[(size_t)m * TT + q];

    float a0 = 0.f, a1 = 0.f;
    if (id >= 0) {
        const int cg = id >> 5;                       // chunk 0..255
        const float* P = PreC + ((size_t)(m * NCH + cg) << 7);
        float s0 = P[lane], s1 = P[64 + lane];
        const int n = id - cg * CH;                   // 0..31, wave-uniform
        const int j = n >> 3;                         // sub-chunk 0..3
        if (j > 0) {
            const float* Sr = Csub + (((size_t)m * NCH + cg) * 3 + (j - 1)) * 128;
            s0 += Sr[lane]; s1 += Sr[64 + lane];
        }
        const float* Kb = Kin + ((size_t)m * TT + (size_t)cg * CH) * DD;
        const float* Vb = X   + ((size_t)m * TT + (size_t)cg * CH) * DD;
        #pragma unroll 1
        for (int tt = j * 8; tt <= n; ++tt) {         // <=8 rows (avg ~4.5)
            float kv = Kb[tt * DD + lane];
            float2 vv = *(const float2*)(Vb + tt * DD);
            s0 = fmaf(kv, vv.x, s0);
            s1 = fmaf(kv, vv.y, s1);
        }
        a0 = qv * s0;
        a1 = qv * s1;
    }
    #pragma unroll
    for (int off = 32; off > 0; off >>= 1) {
        a0 += __shfl_xor(a0, off, 64);
        a1 += __shfl_xor(a1, off, 64);
    }
    __shared__ float red[MODS][2];
    if (lane == 0) { red[m][0] = a0; red[m][1] = a1; }
    __syncthreads();
    if (threadIdx.x == 0) {
        out[(q << 1)]     = red[0][0] + red[1][0] + red[2][0] + red[3][0];
        out[(q << 1) + 1] = red[0][1] + red[1][1] + red[2][1] + red[3][1];
    }
}

extern "C" void kernel_launch(void* const* d_in, const int* in_sizes, int n_in,
                              void* d_out, int out_size, void* d_ws, size_t ws_size,
                              hipStream_t stream)
{
    const float* X    = (const float*)d_in[0];
    const float* wq_w = (const float*)d_in[1];
    const float* wq_b = (const float*)d_in[2];
    const float* wk_w = (const float*)d_in[3];
    const float* wk_b = (const float*)d_in[4];
    float* out = (float*)d_out;

    float* ws    = (float*)d_ws;
    float* Q     = ws;                                    // TT*DD            (2 MB)
    float* K     = Q     + (size_t)TT * DD;               // MODS*TT*DD       (8 MB)
    float* Ctot  = K     + (size_t)MODS * TT * DD;        // MODS*NCH*128     (512 KB)
    float* PreC  = Ctot  + (size_t)MODS * NCH * 128;      // MODS*NCH*128     (512 KB)
    float* Csub  = PreC  + (size_t)MODS * NCH * 128;      // MODS*NCH*3*128   (1.5 MB)
    float* times = Csub  + (size_t)MODS * NCH * 3 * 128;  // MODS*TT          (128 KB)
    int*   idx   = (int*)(times + (size_t)MODS * TT);     // MODS*TT          (128 KB)

    mlp_scan     <<<dim3(128, 5),  256, 0, stream>>>(X, wq_w, wq_b, wk_w, wk_b,
                                                     Q, K, Ctot, Csub, times);
    prefix_find  <<<MODS + 128,    256, 0, stream>>>(Ctot, PreC, times, idx);
    gather_kernel<<<TT,            256, 0, stream>>>(X, Q, K, Csub, PreC, idx, out);
}

// Round 8
// 99.392 us; speedup vs baseline: 1.4159x; 1.4159x over previous
//
#include <hip/hip_runtime.h>

#define TT 8192
#define DD 64
#define MODS 4
#define NCH 256
#define CH  32    // TT / NCH

typedef __attribute__((ext_vector_type(8))) short bf16x8;
typedef __attribute__((ext_vector_type(4))) float f32x4;

// round-to-nearest-even fp32 -> bf16 bits
__device__ __forceinline__ unsigned f2bf1(float x) {
    unsigned u = __float_as_uint(x);
    return (u + 0x7FFFu + ((u >> 16) & 1u)) >> 16;
}
__device__ __forceinline__ unsigned packbf(float a, float b) {
    return f2bf1(a) | (f2bf1(b) << 16);
}

// stage one fp32 W layer [d][c] -> LDS bf16 W^T [c][d] (pitch 72 shorts).
__device__ __forceinline__ void stage_w(const float* __restrict__ Wl,
                                        unsigned short* wb, int c, int dp0)
{
    #pragma unroll
    for (int it = 0; it < 8; ++it) {
        int dp = dp0 + 4 * it;                    // 0..31 (pair of d's)
        float w0 = Wl[(2 * dp)     * DD + c];
        float w1 = Wl[(2 * dp + 1) * DD + c];
        *(unsigned*)&wb[c * 72 + 2 * dp] = packbf(w0, w1);
    }
}

// ---------------------------------------------------------------------------
// Kernel 1: fused MLP (bf16 MFMA) + chunk scan + time extraction.
// (unchanged from round 7 — it fell out of the top-5, working as intended.)
// ---------------------------------------------------------------------------
__global__ __launch_bounds__(256)
void mlp_scan(const float* __restrict__ X,
              const float* __restrict__ wq_w, const float* __restrict__ wq_b,
              const float* __restrict__ wk_w, const float* __restrict__ wk_b,
              float* __restrict__ Q, float* __restrict__ Kout,
              float* __restrict__ Ctot, float* __restrict__ Csub,
              float* __restrict__ times)
{
    __shared__ unsigned short xbuf[4][16][72];   //  9,216 B
    __shared__ unsigned short wbuf[2][64][72];   // 18,432 B
    __shared__ float kbuf[64][68];               // 17,408 B
    __shared__ float2 vstash[64];                //    512 B

    const int job = blockIdx.y;
    const float *xin, *Wj, *Bias;
    float* out;
    if (job == 0) { xin = X; Wj = wq_w; Bias = wq_b; out = Q; }
    else {
        const int m = job - 1;
        xin  = X    + (size_t)m * TT * DD;
        Wj   = wk_w + (size_t)m * 3 * DD * DD;
        Bias = wk_b + (size_t)m * 3 * DD;
        out  = Kout + (size_t)m * TT * DD;
    }

    const int t    = threadIdx.x;
    const int wv   = t >> 6;
    const int lane = t & 63;
    const int quad = lane >> 4;
    const int l15  = lane & 15;
    const int row0 = blockIdx.x * 64 + wv * 16;   // this wave's 16 global rows
    unsigned short* xb = &xbuf[wv][0][0];
    const int wc = t & 63, wdp0 = t >> 6;

    // ---- stage this wave's 16x64 fp32 rows as bf16; stash fp32 V/time ----
    {
        const float4* src = (const float4*)(xin + (size_t)row0 * DD);
        #pragma unroll
        for (int k = 0; k < 4; ++k) {
            int f = lane + 64 * k;                // float4 idx 0..255
            int r = f >> 4, c4 = (f & 15) << 2;   // local-wave row, col
            float4 v = src[f];
            if (job > 0) {
                if ((f & 15) == 0)  vstash[wv * 16 + r] = make_float2(v.x, v.y);
                if ((f & 15) == 15) times[(size_t)(job - 1) * TT + row0 + r] = v.w;
            }
            uint2 p = make_uint2(packbf(v.x, v.y), packbf(v.z, v.w));
            *(uint2*)&xb[r * 72 + c4] = p;
        }
    }

    stage_w(Wj, &wbuf[0][0][0], wc, wdp0);

    #pragma unroll
    for (int l = 0; l < 3; ++l) {
        __syncthreads();
        const unsigned short* wb = &wbuf[l & 1][0][0];
        if (l < 2)
            stage_w(Wj + (size_t)(l + 1) * DD * DD, &wbuf[(l + 1) & 1][0][0], wc, wdp0);

        const float* Bl = Bias + l * DD;
        f32x4 acc[4];
        #pragma unroll
        for (int mt = 0; mt < 4; ++mt) {
            float4 b4 = *(const float4*)(Bl + 16 * mt + quad * 4);
            acc[mt][0] = b4.x; acc[mt][1] = b4.y; acc[mt][2] = b4.z; acc[mt][3] = b4.w;
        }

        bf16x8 xf[2];
        #pragma unroll
        for (int kt = 0; kt < 2; ++kt)
            xf[kt] = *(const bf16x8*)&xb[l15 * 72 + quad * 8 + kt * 32];

        #pragma unroll
        for (int mt = 0; mt < 4; ++mt) {
            #pragma unroll
            for (int kt = 0; kt < 2; ++kt) {
                bf16x8 wf = *(const bf16x8*)&wb[(16 * mt + l15) * 72 + quad * 8 + kt * 32];
                acc[mt] = __builtin_amdgcn_mfma_f32_16x16x32_bf16(wf, xf[kt], acc[mt], 0, 0, 0);
            }
        }

        if (l < 2) {
            #pragma unroll
            for (int mt = 0; mt < 4; ++mt) {
                float r0 = fmaxf(acc[mt][0], 0.f), r1 = fmaxf(acc[mt][1], 0.f);
                float r2 = fmaxf(acc[mt][2], 0.f), r3 = fmaxf(acc[mt][3], 0.f);
                uint2 p = make_uint2(packbf(r0, r1), packbf(r2, r3));
                *(uint2*)&xb[l15 * 72 + 16 * mt + quad * 4] = p;
            }
        } else {
            #pragma unroll
            for (int mt = 0; mt < 4; ++mt) {
                float4 v = make_float4(acc[mt][0], acc[mt][1], acc[mt][2], acc[mt][3]);
                *(float4*)(out + (size_t)(row0 + l15) * DD + 16 * mt + quad * 4) = v;
                if (job > 0)
                    *(float4*)(&kbuf[wv * 16 + l15][16 * mt + quad * 4]) = v;
            }
        }
    }

    // ---- fused chunk scan (jobs 1..4): 2 chunks of 32 rows per block ----
    if (job > 0) {
        __syncthreads();                          // kbuf/vstash complete
        const int m    = job - 1;
        const int chl  = t >> 7;                  // 0..1: local chunk
        const int tid2 = t & 127;
        const int d = tid2 & 63, e = tid2 >> 6;
        const int ch = blockIdx.x * 2 + chl;      // global chunk 0..255
        float acc = 0.f;
        #pragma unroll
        for (int j = 0; j < 4; ++j) {
            #pragma unroll
            for (int s = 0; s < 8; ++s) {
                const int rr = chl * 32 + j * 8 + s;
                float kv = kbuf[rr][d];
                float vv = e ? vstash[rr].y : vstash[rr].x;
                acc = fmaf(kv, vv, acc);
            }
            if (j < 3)
                Csub[(((size_t)m * NCH + ch) * 3 + j) * 128 + tid2] = acc;
        }
        Ctot[((size_t)m * NCH + ch) * 128 + tid2] = acc;
    }
}

// ---------------------------------------------------------------------------
// Kernel 2: fused prefix + search.
// blocks 0..3: per-chunk EXCLUSIVE prefix PreC[m][c], ILP-restructured:
//   pass A: half totals from 128 INDEPENDENT loads (VMEM-pipelined; round
//           7's 128-step dependent chain was the 54 us regression);
//   pass B: 16 batches x 8 independent L2-hot reloads + prefix stores.
// blocks 4..131: per-(q,m) binary search over dense fp32 times (unchanged).
// ---------------------------------------------------------------------------
__global__ __launch_bounds__(256)
void prefix_find(const float* __restrict__ Ctot, float* __restrict__ PreC,
                 const float* __restrict__ times, int* __restrict__ idx)
{
    const int b = blockIdx.x;
    if (b < MODS) {
        __shared__ float hs[128];
        const int sub = threadIdx.x >> 7, t = threadIdx.x & 127;
        const size_t base = ((size_t)b * NCH + (size_t)sub * 128) * 128 + t;

        // pass A: this half's total — independent loads, serial adds only
        float tot = 0.f;
        #pragma unroll 8
        for (int c = 0; c < 128; ++c)
            tot += Ctot[base + (size_t)c * 128];
        if (sub == 0) hs[t] = tot;
        __syncthreads();

        // pass B: exclusive prefix writes, batched 8-wide reloads (L2-hot)
        float run = sub ? hs[t] : 0.f;
        #pragma unroll 1
        for (int bb = 0; bb < 16; ++bb) {
            float v[8];
            #pragma unroll
            for (int i = 0; i < 8; ++i)
                v[i] = Ctot[base + (size_t)(bb * 8 + i) * 128];
            #pragma unroll
            for (int i = 0; i < 8; ++i) {
                PreC[base + (size_t)(bb * 8 + i) * 128] = run;
                run += v[i];
            }
        }
    } else {
        const int bb = b - MODS;                  // 0..127
        const int m  = bb >> 5;
        const int q  = ((bb & 31) << 8) + threadIdx.x;
        const float t1 = times[q];                // modality-0 row IS t1
        const float* t2 = times + (size_t)m * TT;
        int lo = 0, hi = TT;
        #pragma unroll 1
        for (int s = 0; s < 13; ++s) {            // 2^13 == TT
            int mid = (lo + hi) >> 1;
            bool le = (t2[mid] <= t1);
            lo = le ? mid + 1 : lo;
            hi = le ? hi : mid;
        }
        idx[(size_t)m * TT + q] = lo - 1;         // searchsorted(right) - 1
    }
}

// ---------------------------------------------------------------------------
// Kernel 3: gather (unchanged from round 7).
// base = PreC[chunk] + Csub sub-chunk + <=8-row recompute. LDS combine.
// ---------------------------------------------------------------------------
__global__ __launch_bounds__(256)
void gather_kernel(const float* __restrict__ X, const float* __restrict__ Q,
                   const float* __restrict__ Kin, const float* __restrict__ Csub,
                   const float* __restrict__ PreC, const int* __restrict__ idx,
                   float* __restrict__ out)
{
    const int bx   = blockIdx.x;
    const int q    = ((bx & 7) << 10) | (bx >> 3);   // XCD-contiguous q ranges
    const int m    = threadIdx.x >> 6;
    const int lane = threadIdx.x & 63;

    const float qv = Q[(size_t)q * DD + lane];
    const int id = idx[(size_t)m * TT + q];

    float a0 = 0.f, a1 = 0.f;
    if (id >= 0) {
        const int cg = id >> 5;                       // chunk 0..255
        const float* P = PreC + ((size_t)(m * NCH + cg) << 7);
        float s0 = P[lane], s1 = P[64 + lane];
        const int n = id - cg * CH;                   // 0..31, wave-uniform
        const int j = n >> 3;                         // sub-chunk 0..3
        if (j > 0) {
            const float* Sr = Csub + (((size_t)m * NCH + cg) * 3 + (j - 1)) * 128;
            s0 += Sr[lane]; s1 += Sr[64 + lane];
        }
        const float* Kb = Kin + ((size_t)m * TT + (size_t)cg * CH) * DD;
        const float* Vb = X   + ((size_t)m * TT + (size_t)cg * CH) * DD;
        #pragma unroll 1
        for (int tt = j * 8; tt <= n; ++tt) {         // <=8 rows (avg ~4.5)
            float kv = Kb[tt * DD + lane];
            float2 vv = *(const float2*)(Vb + tt * DD);
            s0 = fmaf(kv, vv.x, s0);
            s1 = fmaf(kv, vv.y, s1);
        }
        a0 = qv * s0;
        a1 = qv * s1;
    }
    #pragma unroll
    for (int off = 32; off > 0; off >>= 1) {
        a0 += __shfl_xor(a0, off, 64);
        a1 += __shfl_xor(a1, off, 64);
    }
    __shared__ float red[MODS][2];
    if (lane == 0) { red[m][0] = a0; red[m][1] = a1; }
    __syncthreads();
    if (threadIdx.x == 0) {
        out[(q << 1)]     = red[0][0] + red[1][0] + red[2][0] + red[3][0];
        out[(q << 1) + 1] = red[0][1] + red[1][1] + red[2][1] + red[3][1];
    }
}

extern "C" void kernel_launch(void* const* d_in, const int* in_sizes, int n_in,
                              void* d_out, int out_size, void* d_ws, size_t ws_size,
                              hipStream_t stream)
{
    const float* X    = (const float*)d_in[0];
    const float* wq_w = (const float*)d_in[1];
    const float* wq_b = (const float*)d_in[2];
    const float* wk_w = (const float*)d_in[3];
    const float* wk_b = (const float*)d_in[4];
    float* out = (float*)d_out;

    float* ws    = (float*)d_ws;
    float* Q     = ws;                                    // TT*DD            (2 MB)
    float* K     = Q     + (size_t)TT * DD;               // MODS*TT*DD       (8 MB)
    float* Ctot  = K     + (size_t)MODS * TT * DD;        // MODS*NCH*128     (512 KB)
    float* PreC  = Ctot  + (size_t)MODS * NCH * 128;      // MODS*NCH*128     (512 KB)
    float* Csub  = PreC  + (size_t)MODS * NCH * 128;      // MODS*NCH*3*128   (1.5 MB)
    float* times = Csub  + (size_t)MODS * NCH * 3 * 128;  // MODS*TT          (128 KB)
    int*   idx   = (int*)(times + (size_t)MODS * TT);     // MODS*TT          (128 KB)

    mlp_scan     <<<dim3(128, 5),  256, 0, stream>>>(X, wq_w, wq_b, wk_w, wk_b,
                                                     Q, K, Ctot, Csub, times);
    prefix_find  <<<MODS + 128,    256, 0, stream>>>(Ctot, PreC, times, idx);
    gather_kernel<<<TT,            256, 0, stream>>>(X, Q, K, Csub, PreC, idx, out);
}